// Round 2
// baseline (631.409 us; speedup 1.0000x reference)
//
#include <hip/hip_runtime.h>
#include <hip/hip_bf16.h>

#define T_TOK 8192
#define E_EXP 8
#define DDIM  768
#define FDIM  3072

typedef _Float16 f16x8 __attribute__((ext_vector_type(8)));
typedef _Float16 f16x4 __attribute__((ext_vector_type(4)));
typedef float    f32x4 __attribute__((ext_vector_type(4)));

// ---------------- workspace layout (bytes, all 256-aligned) ----------------
static const size_t XH_OFF   = 0;                         // 8192*768*2   = 12,582,912
static const size_t W1H_OFF  = 12582912;                  // 8*3072*768*2 = 37,748,736
static const size_t Y_OFF    = W1H_OFF;                   // y[16384*768] f16 (reuses w1h region after FC1R)
static const size_t W2H_OFF  = 50331648;                  // 37,748,736
static const size_t WS1H_OFF = 88080384;                  // 4,718,592
static const size_t WS2H_OFF = 92798976;                  // 4,718,592
static const size_t H_OFF    = 97517568;                  // 16384*3072*2 = 100,663,296
static const size_t ROWS_OFF = 198180864;                 // 65,536
static const size_t RW_OFF   = 198246400;                 // 65,536
static const size_t TIDX_OFF = 198311936;                 // 65,536
static const size_t TW_OFF   = 198377472;                 // 65,536
static const size_t CNT_OFF  = 198443008;                 // 256
static const size_t BASE_OFF = 198443264;                 // 256
static const size_t CUR_OFF  = 198443520;                 // 256
static const size_t TSLOT_OFF= 198443776;                 // 65,536 (token -> 2 slots inverse map)
static const size_t WS_NEED  = 198509312;
// NOTE: GEMM prefetch overruns each operand region's last row by <=128 B;
// every GEMM operand region is followed by another workspace region, so all
// reads stay inside [0, WS_NEED). Garbage lands in an LDS slot never read.

// fast gelu: tanh-form via x*sigmoid(2z), z = 0.79788456*(x + 0.044715 x^3)
__device__ inline float fast_gelu(float v) {
    float v2 = v * v;
    float z2n = v * __builtin_fmaf(v2, -0.0713548163f, -1.5957691216f);  // -2z
    float e = __expf(z2n);
    float s = __builtin_amdgcn_rcpf(1.0f + e);
    return v * s;
}

// ---------------- fp32 -> fp16 convert (vectorized) ----------------
__global__ void cvt_f32_f16(const float* __restrict__ src, _Float16* __restrict__ dst, int n4) {
    int i = blockIdx.x * blockDim.x + threadIdx.x;
    if (i >= n4) return;
    float4 v = ((const float4*)src)[i];
    f16x4 o = { (_Float16)v.x, (_Float16)v.y, (_Float16)v.z, (_Float16)v.w };
    *(f16x4*)(dst + 4 * (size_t)i) = o;
}

// ---------------- gate: fp32 logits, top-2, renormalized weights ----------------
__global__ void gate_kernel(const float* __restrict__ x, const float* __restrict__ gw,
                            int* __restrict__ tidx, float* __restrict__ tw) {
    int wave = threadIdx.x >> 6;
    int lane = threadIdx.x & 63;
    int t = blockIdx.x * 4 + wave;
    const float4* xv = (const float4*)(x + (size_t)t * DDIM);
    float p[E_EXP];
#pragma unroll
    for (int e = 0; e < E_EXP; e++) p[e] = 0.f;
    for (int i = lane; i < DDIM / 4; i += 64) {
        float4 xv4 = xv[i];
#pragma unroll
        for (int e = 0; e < E_EXP; e++) {
            float4 g = ((const float4*)(gw + (size_t)e * DDIM))[i];
            p[e] += xv4.x * g.x + xv4.y * g.y + xv4.z * g.z + xv4.w * g.w;
        }
    }
#pragma unroll
    for (int e = 0; e < E_EXP; e++) {
#pragma unroll
        for (int off = 32; off; off >>= 1) p[e] += __shfl_xor(p[e], off);
    }
    if (lane == 0) {
        int i0 = 0;
#pragma unroll
        for (int e = 1; e < E_EXP; e++) if (p[e] > p[i0]) i0 = e;
        int i1 = (i0 == 0) ? 1 : 0;
#pragma unroll
        for (int e = 0; e < E_EXP; e++) {
            if (e == i0) continue;
            if (p[e] > p[i1]) i1 = e;
        }
        float d  = p[i1] - p[i0];          // <= 0
        float e1 = expf(d);
        float w0 = 1.f / (1.f + e1);
        float w1 = 1.f - w0;
        tidx[2 * t]     = i0;  tw[2 * t]     = w0;
        tidx[2 * t + 1] = i1;  tw[2 * t + 1] = w1;
    }
}

// ---------------- count: single block, register histograms ----------------
__global__ void count_kernel(const int* __restrict__ tidx, int* __restrict__ cnt,
                             int* __restrict__ base, int* __restrict__ cur) {
    int c[E_EXP];
#pragma unroll
    for (int e = 0; e < E_EXP; e++) c[e] = 0;
    for (int i = threadIdx.x; i < 2 * T_TOK; i += 1024) {
        int e = tidx[i];
#pragma unroll
        for (int k = 0; k < E_EXP; k++) c[k] += (e == k) ? 1 : 0;
    }
#pragma unroll
    for (int e = 0; e < E_EXP; e++) {
#pragma unroll
        for (int off = 32; off; off >>= 1) c[e] += __shfl_xor(c[e], off);
    }
    __shared__ int wsum[16][E_EXP];
    int lane = threadIdx.x & 63, wave = threadIdx.x >> 6;
    if (lane == 0) {
#pragma unroll
        for (int e = 0; e < E_EXP; e++) wsum[wave][e] = c[e];
    }
    __syncthreads();
    if (threadIdx.x == 0) {
        int acc = 0;
        for (int e = 0; e < E_EXP; e++) {
            int s = 0;
            for (int w = 0; w < 16; w++) s += wsum[w][e];
            cnt[e] = s; base[e] = acc; cur[e] = acc; acc += s;
        }
    }
}

// ---------------- scatter: ballot ranking, 8 atomics per block ----------------
__global__ void scatter_kernel(const int* __restrict__ tidx, const float* __restrict__ tw,
                               int* __restrict__ cur, int* __restrict__ rowsIdx,
                               float* __restrict__ rw, int* __restrict__ tslot) {
    int t = blockIdx.x * 256 + threadIdx.x;
    int lane = threadIdx.x & 63, wave = threadIdx.x >> 6;
    unsigned long long lt = ((unsigned long long)1 << lane) - 1ull;
    __shared__ int wcnt[8][E_EXP];
    __shared__ int wpre[8][E_EXP];
    __shared__ int bbase[E_EXP];

    int myE[2], myR[2];
#pragma unroll
    for (int k = 0; k < 2; k++) {
        int e = tidx[2 * t + k];
        myE[k] = e;
        int vw = wave * 2 + k;
        int rank = 0;
#pragma unroll
        for (int ee = 0; ee < E_EXP; ee++) {
            unsigned long long m = __ballot(e == ee);
            if (e == ee) rank = __builtin_popcountll(m & lt);
            if (lane == 0) wcnt[vw][ee] = __builtin_popcountll(m);
        }
        myR[k] = rank;
    }
    __syncthreads();
    if (threadIdx.x < E_EXP) {
        int e = threadIdx.x, acc = 0;
#pragma unroll
        for (int vw = 0; vw < 8; vw++) { wpre[vw][e] = acc; acc += wcnt[vw][e]; }
        bbase[e] = atomicAdd(&cur[e], acc);
    }
    __syncthreads();
#pragma unroll
    for (int k = 0; k < 2; k++) {
        int e = myE[k];
        int slot = bbase[e] + wpre[wave * 2 + k][e] + myR[k];
        rowsIdx[slot] = t;
        rw[slot] = tw[2 * t + k];
        tslot[2 * t + k] = slot;
    }
}

// ---------------- combine: out[t] += y[s0] + y[s1]  (y already weighted) ----------------
__global__ void combine_kernel(const _Float16* __restrict__ y,
                               const int* __restrict__ tslot,
                               float* __restrict__ out) {
    int idx = blockIdx.x * 256 + threadIdx.x;
    int t = idx / (DDIM / 8);
    int c = (idx % (DDIM / 8)) * 8;
    int s0 = tslot[2 * t], s1 = tslot[2 * t + 1];
    f16x8 a = *(const f16x8*)(y + (size_t)s0 * DDIM + c);
    f16x8 b = *(const f16x8*)(y + (size_t)s1 * DDIM + c);
    float4* o = (float4*)(out + (size_t)t * DDIM + c);
    float4 o0 = o[0], o1 = o[1];
    o0.x += (float)a[0] + (float)b[0];
    o0.y += (float)a[1] + (float)b[1];
    o0.z += (float)a[2] + (float)b[2];
    o0.w += (float)a[3] + (float)b[3];
    o1.x += (float)a[4] + (float)b[4];
    o1.y += (float)a[5] + (float)b[5];
    o1.z += (float)a[6] + (float)b[6];
    o1.w += (float)a[7] + (float)b[7];
    o[0] = o0; o[1] = o1;
}

// ====================== pipelined MFMA GEMM (m201 geometry, ring pipeline) ======================
// Tile 256(M) x 256(N), BK=32, 512 threads = 8 waves (2M x 4N), per-wave 128x64.
// LDS 128 KB: A = 4-slot ring (4 x 16 KB), B = 4-slot ring (4 x 16 KB).
// Iter t (one K-tile, 2 phases) consumes slot t&3 and stages tile t+2 into
// slot (t+2)&3 (held tile t-2, dead >=4 phases -> no overwrite race).
// Phase: {4-8 ds_read_b128 | 2 global_load_lds} -> s_barrier -> setprio(1)
// -> 16 MFMA -> setprio(0) -> s_barrier; vmcnt(4) once per iter (never 0).
// Stage->wait distance = 4 phases (~2400 cyc >> 900-cyc HBM latency).
#define FC1S 0
#define FC2S 1
#define FC1R 2
#define FC2R 3

#define GLL(p, off16) __builtin_amdgcn_global_load_lds( \
    (const __attribute__((address_space(1))) void*)(p), \
    (__attribute__((address_space(3))) void*)(sm + (off16)), 16, 0, 0)

// A tile (256x32) -> slot sl: rows r0 -> half0, rows 128+r0 -> half1
#define STAGE_A(sl, ko) do { \
    GLL(pA0 + (ko), (sl)*8192 +        wid*512); \
    GLL(pA1 + (ko), (sl)*8192 + 4096 + wid*512); \
} while (0)

#define STAGE_B(sl, ko) do { \
    GLL(pB0 + (ko), 32768 + (sl)*8192 +        wid*512); \
    GLL(pB1 + (ko), 32768 + (sl)*8192 + 4096 + wid*512); \
} while (0)

template <int MODE>
__global__ __launch_bounds__(512, 2) void gemm_kernel(
    const _Float16* __restrict__ Abase,   // xh (fc1) or h (fc2), lda == K
    const _Float16* __restrict__ Wbase,   // [N,K] row-major (per expert for routed)
    const float* __restrict__ biasBase,
    _Float16* __restrict__ h,             // fc1 output; y scratch for FC2R
    float* __restrict__ out,              // fc2 shared output
    const int* __restrict__ cnt, const int* __restrict__ base,
    const int* __restrict__ rowsIdx, const float* __restrict__ rw)
{
    constexpr int K = (MODE == FC1S || MODE == FC1R) ? DDIM : FDIM;
    constexpr int N = (MODE == FC1S || MODE == FC1R) ? FDIM : DDIM;
    constexpr bool ROUTED = (MODE == FC1R || MODE == FC2R);
    constexpr int NT = K / 32;            // K-tiles

    int m0, mEnd;
    const _Float16* W;
    const float* bias;
    if constexpr (ROUTED) {
        int bx = blockIdx.x, accb = 0, expert = -1, rb = 0;
#pragma unroll
        for (int e = 0; e < E_EXP; e++) {
            int nb = (cnt[e] + 255) >> 8;
            if (expert < 0 && bx < accb + nb) { expert = e; rb = bx - accb; }
            accb += nb;
        }
        if (expert < 0) return;
        m0   = base[expert] + rb * 256;
        mEnd = base[expert] + cnt[expert];
        W    = Wbase + (size_t)expert * N * K;
        bias = biasBase + (size_t)expert * N;
    } else {
        m0 = blockIdx.x * 256;
        mEnd = T_TOK;
        W = Wbase;
        bias = biasBase;
    }
    int n0 = blockIdx.y * 256;

    // A ring: f16 [0, 32768) = 4 slots x 8192; B ring: [32768, 65536).
    // Slot layout: row r (0..255) x 32 k; row = 64 B = 4 chunks of 16 B;
    // chunk c of row r stored at position c ^ (r&3) (uniform 2-way banks).
    __shared__ __align__(16) _Float16 sm[65536];

    int tid  = threadIdx.x;
    int lane = tid & 63;
    int wid  = tid >> 6;            // 0..7
    int wm   = wid >> 2;            // 0..1 (M: 128 rows each)
    int wn   = wid & 3;             // 0..3 (N: 64 cols each)
    int m16  = lane & 15, q = lane >> 4;
    int x3   = m16 & 3;

    f32x4 acc[8][4];
#pragma unroll
    for (int i = 0; i < 8; i++)
#pragma unroll
        for (int j = 0; j < 4; j++) acc[i][j] = f32x4{0.f, 0.f, 0.f, 0.f};

    // ---- staging sources: thread covers 16B chunk tid (rows 0..127) and
    // tid+512 (rows 128..255) of each 16 KB tile; same swizzled source chunk.
    int r0  = tid >> 2;                       // 0..127
    int cSw = (tid & 3) ^ (r0 & 3);
    const _Float16 *pA0, *pA1, *pB0, *pB1;
    {
        int pr0 = m0 + r0,       pr1 = m0 + 128 + r0;
        bool v0 = pr0 < mEnd,    v1 = pr1 < mEnd;
        int ar0, ar1;
        if constexpr (MODE == FC1R) {
            ar0 = rowsIdx[v0 ? pr0 : m0];
            ar1 = rowsIdx[v1 ? pr1 : m0];
        } else {
            ar0 = v0 ? pr0 : m0;
            ar1 = v1 ? pr1 : m0;
        }
        pA0 = Abase + (size_t)ar0 * K + cSw * 8;
        pA1 = Abase + (size_t)ar1 * K + cSw * 8;
    }
    pB0 = W + (size_t)(n0 +       r0) * K + cSw * 8;
    pB1 = W + (size_t)(n0 + 128 + r0) * K + cSw * 8;

    // ---- LDS read bases (f16 offsets; + sl*8192 per iter, + i*512 / + j*512)
    int aRd = (wm * 128 + m16) * 32 + (q ^ x3) * 8;
    int bRd = 32768 + (wn * 64 + m16) * 32 + (q ^ x3) * 8;

    // ---- prologue: stage tiles 0,1 (8 loads); wait tile0 (4 newest in flight)
    STAGE_A(0, 0);  STAGE_B(0, 0);
    STAGE_A(1, 32); STAGE_B(1, 32);
    asm volatile("s_waitcnt vmcnt(4)" ::: "memory");
    __builtin_amdgcn_s_barrier();

#pragma unroll 4
    for (int t = 0; t < NT; ++t) {
        int sl = t & 3, s2 = (t + 2) & 3;
        f16x8 af[4], bf[4];
        // ---- phase A: B frags + A frags i0..3; stage A(t+2)
#pragma unroll
        for (int j = 0; j < 4; j++)
            bf[j] = *(const f16x8*)(sm + sl * 8192 + bRd + j * 512);
#pragma unroll
        for (int i = 0; i < 4; i++)
            af[i] = *(const f16x8*)(sm + sl * 8192 + aRd + i * 512);
        STAGE_A(s2, 64);
        __builtin_amdgcn_s_barrier();
        __builtin_amdgcn_s_setprio(1);
#pragma unroll
        for (int i = 0; i < 4; i++)
#pragma unroll
            for (int j = 0; j < 4; j++)
                acc[i][j] = __builtin_amdgcn_mfma_f32_16x16x32_f16(af[i], bf[j], acc[i][j], 0, 0, 0);
        __builtin_amdgcn_s_setprio(0);
        __builtin_amdgcn_s_barrier();
        // ---- phase B: A frags i4..7; stage B(t+2)
#pragma unroll
        for (int i = 0; i < 4; i++)
            af[i] = *(const f16x8*)(sm + sl * 8192 + aRd + (4 + i) * 512);
        STAGE_B(s2, 64);
        __builtin_amdgcn_s_barrier();
        __builtin_amdgcn_s_setprio(1);
#pragma unroll
        for (int i = 0; i < 4; i++)
#pragma unroll
            for (int j = 0; j < 4; j++)
                acc[4 + i][j] = __builtin_amdgcn_mfma_f32_16x16x32_f16(af[i], bf[j], acc[4 + i][j], 0, 0, 0);
        __builtin_amdgcn_s_setprio(0);
        asm volatile("s_waitcnt vmcnt(4)" ::: "memory");
        __builtin_amdgcn_s_barrier();
        pA0 += 32; pA1 += 32; pB0 += 32; pB1 += 32;
    }

    // drain leftover (garbage) prefetch
    asm volatile("s_waitcnt vmcnt(0)" ::: "memory");

    // ---- epilogue. C/D layout: col = lane&15, row = (lane>>4)*4 + reg
    float biasv[4];
#pragma unroll
    for (int j = 0; j < 4; j++) biasv[j] = bias[n0 + wn * 64 + j * 16 + m16];

#pragma unroll
    for (int i = 0; i < 8; i++) {
#pragma unroll
        for (int r = 0; r < 4; r++) {
            int rowp = m0 + wm * 128 + i * 16 + q * 4 + r;
            if (rowp >= mEnd) continue;
            float wgt = 0.f;
            if constexpr (MODE == FC2R) wgt = rw[rowp];
#pragma unroll
            for (int j = 0; j < 4; j++) {
                int col = n0 + wn * 64 + j * 16 + m16;
                float v = acc[i][j][r] + biasv[j];
                if constexpr (MODE == FC1S || MODE == FC1R) {
                    v = fast_gelu(v);
                    h[(size_t)rowp * FDIM + col] = (_Float16)v;
                } else if constexpr (MODE == FC2S) {
                    out[(size_t)rowp * DDIM + col] = v;                // rowp == token
                } else {                                               // FC2R: weighted f16 to y
                    h[(size_t)rowp * DDIM + col] = (_Float16)(v * wgt);
                }
            }
        }
    }
}

#undef GLL
#undef STAGE_A
#undef STAGE_B

// ---------------- launch ----------------
extern "C" void kernel_launch(void* const* d_in, const int* in_sizes, int n_in,
                              void* d_out, int out_size, void* d_ws, size_t ws_size,
                              hipStream_t stream) {
    const float* x   = (const float*)d_in[0];
    const float* gw  = (const float*)d_in[1];
    const float* w1  = (const float*)d_in[2];
    const float* b1  = (const float*)d_in[3];
    const float* w2  = (const float*)d_in[4];
    const float* b2  = (const float*)d_in[5];
    const float* ws1 = (const float*)d_in[6];
    const float* bs1 = (const float*)d_in[7];
    const float* ws2 = (const float*)d_in[8];
    const float* bs2 = (const float*)d_in[9];
    float* out = (float*)d_out;
    char* ws = (char*)d_ws;
    if (ws_size < WS_NEED) return;   // fail loudly (output stays zero)

    _Float16* xh   = (_Float16*)(ws + XH_OFF);
    _Float16* w1h  = (_Float16*)(ws + W1H_OFF);
    _Float16* yb   = (_Float16*)(ws + Y_OFF);     // aliases w1h (dead after FC1R)
    _Float16* w2h  = (_Float16*)(ws + W2H_OFF);
    _Float16* ws1h = (_Float16*)(ws + WS1H_OFF);
    _Float16* ws2h = (_Float16*)(ws + WS2H_OFF);
    _Float16* h    = (_Float16*)(ws + H_OFF);
    int*   rowsIdx = (int*)(ws + ROWS_OFF);
    float* rw      = (float*)(ws + RW_OFF);
    int*   tidx    = (int*)(ws + TIDX_OFF);
    float* tw      = (float*)(ws + TW_OFF);
    int*   cnt     = (int*)(ws + CNT_OFF);
    int*   base    = (int*)(ws + BASE_OFF);
    int*   cur     = (int*)(ws + CUR_OFF);
    int*   tslot   = (int*)(ws + TSLOT_OFF);

    // conversions to fp16
    cvt_f32_f16<<<6144,  256, 0, stream>>>(x,   xh,   1572864);
    cvt_f32_f16<<<18432, 256, 0, stream>>>(w1,  w1h,  4718592);
    cvt_f32_f16<<<18432, 256, 0, stream>>>(w2,  w2h,  4718592);
    cvt_f32_f16<<<2304,  256, 0, stream>>>(ws1, ws1h, 589824);
    cvt_f32_f16<<<2304,  256, 0, stream>>>(ws2, ws2h, 589824);

    // routing (atomic-free count + low-contention scatter)
    gate_kernel<<<2048, 256, 0, stream>>>(x, gw, tidx, tw);
    count_kernel<<<1, 1024, 0, stream>>>(tidx, cnt, base, cur);
    scatter_kernel<<<32, 256, 0, stream>>>(tidx, tw, cur, rowsIdx, rw, tslot);

    // shared expert, then routed; FC2R writes weighted f16 into yb
    // routed grid.x: sum_e ceil(cnt_e/256) <= 64 + 8 = 72
    gemm_kernel<FC1S><<<dim3(32, 12), 512, 0, stream>>>(xh, ws1h, bs1, h, out, cnt, base, rowsIdx, rw);
    gemm_kernel<FC2S><<<dim3(32, 3),  512, 0, stream>>>(h,  ws2h, bs2, h, out, cnt, base, rowsIdx, rw);
    gemm_kernel<FC1R><<<dim3(72, 12), 512, 0, stream>>>(xh, w1h,  b1,  h, out, cnt, base, rowsIdx, rw);
    gemm_kernel<FC2R><<<dim3(72, 3),  512, 0, stream>>>(h,  w2h,  b2,  yb, out, cnt, base, rowsIdx, rw);

    // final combine: out[t] += y[slot0] + y[slot1]
    combine_kernel<<<3072, 256, 0, stream>>>(yb, tslot, out);
}

// Round 5
// 593.108 us; speedup vs baseline: 1.0646x; 1.0646x over previous
//
#include <hip/hip_runtime.h>
#include <hip/hip_bf16.h>

#define T_TOK 8192
#define E_EXP 8
#define DDIM  768
#define FDIM  3072

typedef _Float16 f16x8 __attribute__((ext_vector_type(8)));
typedef _Float16 f16x4 __attribute__((ext_vector_type(4)));
typedef float    f32x4 __attribute__((ext_vector_type(4)));

// ---------------- workspace layout (bytes, all 256-aligned) ----------------
static const size_t XH_OFF   = 0;                         // 8192*768*2   = 12,582,912
static const size_t W1H_OFF  = 12582912;                  // 8*3072*768*2 = 37,748,736
static const size_t Y_OFF    = W1H_OFF;                   // y[16384*768] f16 (reuses w1h region after FC1R)
static const size_t W2H_OFF  = 50331648;                  // 37,748,736
static const size_t WS1H_OFF = 88080384;                  // 4,718,592
static const size_t WS2H_OFF = 92798976;                  // 4,718,592
static const size_t H_OFF    = 97517568;                  // 16384*3072*2 = 100,663,296
static const size_t ROWS_OFF = 198180864;                 // 65,536
static const size_t RW_OFF   = 198246400;                 // 65,536
static const size_t TIDX_OFF = 198311936;                 // 65,536
static const size_t TW_OFF   = 198377472;                 // 65,536
static const size_t CNT_OFF  = 198443008;                 // 256
static const size_t BASE_OFF = 198443264;                 // 256
static const size_t CUR_OFF  = 198443520;                 // 256
static const size_t TSLOT_OFF= 198443776;                 // 65,536 (token -> 2 slots inverse map)
static const size_t WS_NEED  = 198509312;

// fast gelu: tanh-form via x*sigmoid(2z), z = 0.79788456*(x + 0.044715 x^3)
__device__ inline float fast_gelu(float v) {
    float v2 = v * v;
    float z2n = v * __builtin_fmaf(v2, -0.0713548163f, -1.5957691216f);  // -2z
    float e = __expf(z2n);
    float s = __builtin_amdgcn_rcpf(1.0f + e);
    return v * s;
}

// ---------------- fp32 -> fp16 convert (vectorized) ----------------
__global__ void cvt_f32_f16(const float* __restrict__ src, _Float16* __restrict__ dst, int n4) {
    int i = blockIdx.x * blockDim.x + threadIdx.x;
    if (i >= n4) return;
    float4 v = ((const float4*)src)[i];
    f16x4 o = { (_Float16)v.x, (_Float16)v.y, (_Float16)v.z, (_Float16)v.w };
    *(f16x4*)(dst + 4 * (size_t)i) = o;
}

// ---------------- gate: fp32 logits, top-2, renormalized weights ----------------
__global__ void gate_kernel(const float* __restrict__ x, const float* __restrict__ gw,
                            int* __restrict__ tidx, float* __restrict__ tw) {
    int wave = threadIdx.x >> 6;
    int lane = threadIdx.x & 63;
    int t = blockIdx.x * 4 + wave;
    const float4* xv = (const float4*)(x + (size_t)t * DDIM);
    float p[E_EXP];
#pragma unroll
    for (int e = 0; e < E_EXP; e++) p[e] = 0.f;
    for (int i = lane; i < DDIM / 4; i += 64) {
        float4 xv4 = xv[i];
#pragma unroll
        for (int e = 0; e < E_EXP; e++) {
            float4 g = ((const float4*)(gw + (size_t)e * DDIM))[i];
            p[e] += xv4.x * g.x + xv4.y * g.y + xv4.z * g.z + xv4.w * g.w;
        }
    }
#pragma unroll
    for (int e = 0; e < E_EXP; e++) {
#pragma unroll
        for (int off = 32; off; off >>= 1) p[e] += __shfl_xor(p[e], off);
    }
    if (lane == 0) {
        int i0 = 0;
#pragma unroll
        for (int e = 1; e < E_EXP; e++) if (p[e] > p[i0]) i0 = e;
        int i1 = (i0 == 0) ? 1 : 0;
#pragma unroll
        for (int e = 0; e < E_EXP; e++) {
            if (e == i0) continue;
            if (p[e] > p[i1]) i1 = e;
        }
        float d  = p[i1] - p[i0];          // <= 0
        float e1 = expf(d);
        float w0 = 1.f / (1.f + e1);
        float w1 = 1.f - w0;
        tidx[2 * t]     = i0;  tw[2 * t]     = w0;
        tidx[2 * t + 1] = i1;  tw[2 * t + 1] = w1;
    }
}

// ---------------- count: single block, register histograms ----------------
__global__ void count_kernel(const int* __restrict__ tidx, int* __restrict__ cnt,
                             int* __restrict__ base, int* __restrict__ cur) {
    int c[E_EXP];
#pragma unroll
    for (int e = 0; e < E_EXP; e++) c[e] = 0;
    for (int i = threadIdx.x; i < 2 * T_TOK; i += 1024) {
        int e = tidx[i];
#pragma unroll
        for (int k = 0; k < E_EXP; k++) c[k] += (e == k) ? 1 : 0;
    }
#pragma unroll
    for (int e = 0; e < E_EXP; e++) {
#pragma unroll
        for (int off = 32; off; off >>= 1) c[e] += __shfl_xor(c[e], off);
    }
    __shared__ int wsum[16][E_EXP];
    int lane = threadIdx.x & 63, wave = threadIdx.x >> 6;
    if (lane == 0) {
#pragma unroll
        for (int e = 0; e < E_EXP; e++) wsum[wave][e] = c[e];
    }
    __syncthreads();
    if (threadIdx.x == 0) {
        int acc = 0;
        for (int e = 0; e < E_EXP; e++) {
            int s = 0;
            for (int w = 0; w < 16; w++) s += wsum[w][e];
            cnt[e] = s; base[e] = acc; cur[e] = acc; acc += s;
        }
    }
}

// ---------------- scatter: ballot ranking, 8 atomics per block ----------------
__global__ void scatter_kernel(const int* __restrict__ tidx, const float* __restrict__ tw,
                               int* __restrict__ cur, int* __restrict__ rowsIdx,
                               float* __restrict__ rw, int* __restrict__ tslot) {
    int t = blockIdx.x * 256 + threadIdx.x;
    int lane = threadIdx.x & 63, wave = threadIdx.x >> 6;
    unsigned long long lt = ((unsigned long long)1 << lane) - 1ull;
    __shared__ int wcnt[8][E_EXP];
    __shared__ int wpre[8][E_EXP];
    __shared__ int bbase[E_EXP];

    int myE[2], myR[2];
#pragma unroll
    for (int k = 0; k < 2; k++) {
        int e = tidx[2 * t + k];
        myE[k] = e;
        int vw = wave * 2 + k;
        int rank = 0;
#pragma unroll
        for (int ee = 0; ee < E_EXP; ee++) {
            unsigned long long m = __ballot(e == ee);
            if (e == ee) rank = __builtin_popcountll(m & lt);
            if (lane == 0) wcnt[vw][ee] = __builtin_popcountll(m);
        }
        myR[k] = rank;
    }
    __syncthreads();
    if (threadIdx.x < E_EXP) {
        int e = threadIdx.x, acc = 0;
#pragma unroll
        for (int vw = 0; vw < 8; vw++) { wpre[vw][e] = acc; acc += wcnt[vw][e]; }
        bbase[e] = atomicAdd(&cur[e], acc);
    }
    __syncthreads();
#pragma unroll
    for (int k = 0; k < 2; k++) {
        int e = myE[k];
        int slot = bbase[e] + wpre[wave * 2 + k][e] + myR[k];
        rowsIdx[slot] = t;
        rw[slot] = tw[2 * t + k];
        tslot[2 * t + k] = slot;
    }
}

// ---------------- combine: out[t] += y[s0] + y[s1]  (y already weighted) ----------------
__global__ void combine_kernel(const _Float16* __restrict__ y,
                               const int* __restrict__ tslot,
                               float* __restrict__ out) {
    int idx = blockIdx.x * 256 + threadIdx.x;
    int t = idx / (DDIM / 8);
    int c = (idx % (DDIM / 8)) * 8;
    int s0 = tslot[2 * t], s1 = tslot[2 * t + 1];
    f16x8 a = *(const f16x8*)(y + (size_t)s0 * DDIM + c);
    f16x8 b = *(const f16x8*)(y + (size_t)s1 * DDIM + c);
    float4* o = (float4*)(out + (size_t)t * DDIM + c);
    float4 o0 = o[0], o1 = o[1];
    o0.x += (float)a[0] + (float)b[0];
    o0.y += (float)a[1] + (float)b[1];
    o0.z += (float)a[2] + (float)b[2];
    o0.w += (float)a[3] + (float)b[3];
    o1.x += (float)a[4] + (float)b[4];
    o1.y += (float)a[5] + (float)b[5];
    o1.z += (float)a[6] + (float)b[6];
    o1.w += (float)a[7] + (float)b[7];
    o[0] = o0; o[1] = o1;
}

// ====================== pipelined MFMA GEMM (3-slot ring, depth-2 prefetch) ======================
// Tile 256(M) x 128(N), BK=64, 512 threads = 8 waves (4M x 2N), per-wave 64x64.
// LDS 144 KB: A = 3 slots x 32 KB, B = 3 slots x 16 KB.  Iter t consumes slot
// t%3 and stages tile t+2 into slot (t+2)%3 (holds tile t-1, fully read before
// the end-of-iter-(t-1) barrier -> overwrite-safe; R2-proven pattern).
// ONE wait + ONE barrier per K-tile: vmcnt(6) at iter end drains tile t+1's 6
// loads (issued one full tile ~2400cyc earlier >> 900cyc HBM latency) and
// leaves tile t+2's 6 in flight (never drains to 0 in-loop; margin = 6).
// No intra-tile barriers: all reads hit slot sl, all writes hit slot s2.
// Row = 64 f16 = 128 B = 8 chunks of 16 B; chunk c of row r stored at c^(r&7)
// (conflict-free b128 reads, 0 conflicts measured in R0/R1).
#define FC1S 0
#define FC2S 1
#define FC1R 2
#define FC2R 3

#define GLL(p, off16) __builtin_amdgcn_global_load_lds( \
    (const __attribute__((address_space(1))) void*)(p), \
    (__attribute__((address_space(3))) void*)(sm + (off16)), 16, 0, 0)
#define BARRIER __builtin_amdgcn_s_barrier()
#define PRIO1 __builtin_amdgcn_s_setprio(1)
#define PRIO0 __builtin_amdgcn_s_setprio(0)
#define VM6 asm volatile("s_waitcnt vmcnt(6)" ::: "memory")
#define VM0 asm volatile("s_waitcnt vmcnt(0)" ::: "memory")

// one K-tile: S = slot (compile-time 0/1/2), T = tile index (runtime)
#define TILE(S, T) do { \
    if ((T) + 2 < NT) { \
        constexpr int S2 = ((S) + 2) % 3; \
        GLL(pA[0] + 128, S2 * 16384 +         wid * 512); \
        GLL(pA[1] + 128, S2 * 16384 +  4096 + wid * 512); \
        GLL(pA[2] + 128, S2 * 16384 +  8192 + wid * 512); \
        GLL(pA[3] + 128, S2 * 16384 + 12288 + wid * 512); \
        GLL(pB[0] + 128, 49152 + S2 * 8192 +        wid * 512); \
        GLL(pB[1] + 128, 49152 + S2 * 8192 + 4096 + wid * 512); \
    } \
    { \
        f16x8 af0[4], af1[4], bf0[4], bf1[4]; \
        _Pragma("unroll") \
        for (int i = 0; i < 4; i++) { \
            af0[i] = *(const f16x8*)(sm + (S) * 16384 + aRd + i * 1024 + ch0); \
            af1[i] = *(const f16x8*)(sm + (S) * 16384 + aRd + i * 1024 + ch1); \
        } \
        _Pragma("unroll") \
        for (int j = 0; j < 4; j++) { \
            bf0[j] = *(const f16x8*)(sm + 49152 + (S) * 8192 + bRd + j * 1024 + ch0); \
            bf1[j] = *(const f16x8*)(sm + 49152 + (S) * 8192 + bRd + j * 1024 + ch1); \
        } \
        PRIO1; \
        _Pragma("unroll") \
        for (int i = 0; i < 4; i++) \
            _Pragma("unroll") \
            for (int j = 0; j < 4; j++) \
                acc[i][j] = __builtin_amdgcn_mfma_f32_16x16x32_f16(af0[i], bf0[j], acc[i][j], 0, 0, 0); \
        _Pragma("unroll") \
        for (int i = 0; i < 4; i++) \
            _Pragma("unroll") \
            for (int j = 0; j < 4; j++) \
                acc[i][j] = __builtin_amdgcn_mfma_f32_16x16x32_f16(af1[i], bf1[j], acc[i][j], 0, 0, 0); \
        PRIO0; \
    } \
    if ((T) < NT - 2) { VM6; } else if ((T) == NT - 2) { VM0; } \
    BARRIER; \
    _Pragma("unroll") \
    for (int g = 0; g < 4; g++) pA[g] += 64; \
    pB[0] += 64; pB[1] += 64; \
} while (0)

template <int MODE>
__global__ __launch_bounds__(512, 2) void gemm_kernel(
    const _Float16* __restrict__ Abase,   // xh (fc1) or h (fc2), lda == K
    const _Float16* __restrict__ Wbase,   // [N,K] row-major (per expert for routed)
    const float* __restrict__ biasBase,
    _Float16* __restrict__ h,             // fc1 output; y scratch for FC2R
    float* __restrict__ out,              // fc2 shared output
    const int* __restrict__ cnt, const int* __restrict__ base,
    const int* __restrict__ rowsIdx, const float* __restrict__ rw)
{
    constexpr int K = (MODE == FC1S || MODE == FC1R) ? DDIM : FDIM;
    constexpr int N = (MODE == FC1S || MODE == FC1R) ? FDIM : DDIM;
    constexpr bool ROUTED = (MODE == FC1R || MODE == FC2R);
    constexpr int NT = K / 64;            // K-tiles (12 or 48, both % 3 == 0)
    static_assert(NT % 3 == 0, "ring unroll needs NT % 3 == 0");

    int m0, mEnd;
    const _Float16* W;
    const float* bias;
    if constexpr (ROUTED) {
        int bx = blockIdx.x, accb = 0, expert = -1, rb = 0;
#pragma unroll
        for (int e = 0; e < E_EXP; e++) {
            int nb = (cnt[e] + 255) >> 8;
            if (expert < 0 && bx < accb + nb) { expert = e; rb = bx - accb; }
            accb += nb;
        }
        if (expert < 0) return;
        m0   = base[expert] + rb * 256;
        mEnd = base[expert] + cnt[expert];
        W    = Wbase + (size_t)expert * N * K;
        bias = biasBase + (size_t)expert * N;
    } else {
        m0 = blockIdx.x * 256;
        mEnd = T_TOK;
        W = Wbase;
        bias = biasBase;
    }
    int n0 = blockIdx.y * 128;

    // A slots: f16 [0, 49152) = 3 x 16384; B slots: [49152, 73728) = 3 x 8192.
    // Within a slot: row r at r*64, chunk c at position c^(r&7).
    __shared__ __align__(16) _Float16 sm[73728];

    int tid  = threadIdx.x;
    int lane = tid & 63;
    int wid  = tid >> 6;            // 0..7
    int wm   = wid >> 1;            // 0..3 (M: 64 rows each)
    int wn   = wid & 1;             // 0..1 (N: 64 cols each)
    int m16  = lane & 15, q = lane >> 4;
    int x7   = m16 & 7;

    f32x4 acc[4][4];
#pragma unroll
    for (int i = 0; i < 4; i++)
#pragma unroll
        for (int j = 0; j < 4; j++) acc[i][j] = f32x4{0.f, 0.f, 0.f, 0.f};

    // ---- staging: thread covers 16B chunk tid of each 8 KB group (64 rows);
    // A groups g=0..3 (rows m0+64g+r0), B groups g=0..1 (rows n0+64g+r0).
    int r0  = tid >> 3;                       // 0..63
    int cSw = (tid & 7) ^ (r0 & 7);
    const _Float16 *pA[4], *pB[2];
#pragma unroll
    for (int g = 0; g < 4; g++) {
        int pr = m0 + g * 64 + r0;
        bool valid = pr < mEnd;
        int ar;
        if constexpr (MODE == FC1R) ar = rowsIdx[valid ? pr : m0];
        else                        ar = valid ? pr : m0;
        pA[g] = Abase + (size_t)ar * K + cSw * 8;
    }
#pragma unroll
    for (int g = 0; g < 2; g++)
        pB[g] = W + (size_t)(n0 + g * 64 + r0) * K + cSw * 8;

    // ---- LDS read bases (f16 offsets)
    int aRd = (wm * 64 + m16) * 64;           // + slot*16384 + i*1024 + ch
    int bRd = (wn * 64 + m16) * 64;           // + 49152 + slot*8192 + j*1024 + ch
    int ch0 = (q ^ x7) * 8;                   // ks = 0
    int ch1 = ((4 + q) ^ x7) * 8;             // ks = 1

    // ---- prologue: stage tile0 -> slot0, tile1 -> slot1 (12 loads);
    // vmcnt(6) drains tile0's 6, leaves tile1's 6 in flight (steady-state inv.)
    GLL(pA[0], 0 +         wid * 512);
    GLL(pA[1], 0 +  4096 + wid * 512);
    GLL(pA[2], 0 +  8192 + wid * 512);
    GLL(pA[3], 0 + 12288 + wid * 512);
    GLL(pB[0], 49152 +        wid * 512);
    GLL(pB[1], 49152 + 4096 + wid * 512);
    GLL(pA[0] + 64, 16384 +         wid * 512);
    GLL(pA[1] + 64, 16384 +  4096 + wid * 512);
    GLL(pA[2] + 64, 16384 +  8192 + wid * 512);
    GLL(pA[3] + 64, 16384 + 12288 + wid * 512);
    GLL(pB[0] + 64, 49152 + 8192 +        wid * 512);
    GLL(pB[1] + 64, 49152 + 8192 + 4096 + wid * 512);
    VM6;
    BARRIER;

    for (int t3 = 0; t3 < NT; t3 += 3) {
        TILE(0, t3 + 0);
        TILE(1, t3 + 1);
        TILE(2, t3 + 2);
    }
    VM0;   // safety (queue already empty after t = NT-2's drain)

    // ---- epilogue. C/D layout: col = lane&15, row = (lane>>4)*4 + reg
    float biasv[4];
#pragma unroll
    for (int j = 0; j < 4; j++) biasv[j] = bias[n0 + wn * 64 + j * 16 + m16];

#pragma unroll
    for (int i = 0; i < 4; i++) {
#pragma unroll
        for (int r = 0; r < 4; r++) {
            int rowp = m0 + wm * 64 + i * 16 + q * 4 + r;
            if (rowp >= mEnd) continue;
            float wgt = 0.f;
            if constexpr (MODE == FC2R) wgt = rw[rowp];
#pragma unroll
            for (int j = 0; j < 4; j++) {
                int col = n0 + wn * 64 + j * 16 + m16;
                float v = acc[i][j][r] + biasv[j];
                if constexpr (MODE == FC1S || MODE == FC1R) {
                    v = fast_gelu(v);
                    h[(size_t)rowp * FDIM + col] = (_Float16)v;
                } else if constexpr (MODE == FC2S) {
                    out[(size_t)rowp * DDIM + col] = v;                // rowp == token
                } else {                                               // FC2R: weighted f16 to y
                    h[(size_t)rowp * DDIM + col] = (_Float16)(v * wgt);
                }
            }
        }
    }
}

#undef GLL
#undef BARRIER
#undef PRIO1
#undef PRIO0
#undef VM6
#undef VM0
#undef TILE

// ---------------- launch ----------------
extern "C" void kernel_launch(void* const* d_in, const int* in_sizes, int n_in,
                              void* d_out, int out_size, void* d_ws, size_t ws_size,
                              hipStream_t stream) {
    const float* x   = (const float*)d_in[0];
    const float* gw  = (const float*)d_in[1];
    const float* w1  = (const float*)d_in[2];
    const float* b1  = (const float*)d_in[3];
    const float* w2  = (const float*)d_in[4];
    const float* b2  = (const float*)d_in[5];
    const float* ws1 = (const float*)d_in[6];
    const float* bs1 = (const float*)d_in[7];
    const float* ws2 = (const float*)d_in[8];
    const float* bs2 = (const float*)d_in[9];
    float* out = (float*)d_out;
    char* ws = (char*)d_ws;
    if (ws_size < WS_NEED) return;   // fail loudly (output stays zero)

    _Float16* xh   = (_Float16*)(ws + XH_OFF);
    _Float16* w1h  = (_Float16*)(ws + W1H_OFF);
    _Float16* yb   = (_Float16*)(ws + Y_OFF);     // aliases w1h (dead after FC1R)
    _Float16* w2h  = (_Float16*)(ws + W2H_OFF);
    _Float16* ws1h = (_Float16*)(ws + WS1H_OFF);
    _Float16* ws2h = (_Float16*)(ws + WS2H_OFF);
    _Float16* h    = (_Float16*)(ws + H_OFF);
    int*   rowsIdx = (int*)(ws + ROWS_OFF);
    float* rw      = (float*)(ws + RW_OFF);
    int*   tidx    = (int*)(ws + TIDX_OFF);
    float* tw      = (float*)(ws + TW_OFF);
    int*   cnt     = (int*)(ws + CNT_OFF);
    int*   base    = (int*)(ws + BASE_OFF);
    int*   cur     = (int*)(ws + CUR_OFF);
    int*   tslot   = (int*)(ws + TSLOT_OFF);

    // conversions to fp16
    cvt_f32_f16<<<6144,  256, 0, stream>>>(x,   xh,   1572864);
    cvt_f32_f16<<<18432, 256, 0, stream>>>(w1,  w1h,  4718592);
    cvt_f32_f16<<<18432, 256, 0, stream>>>(w2,  w2h,  4718592);
    cvt_f32_f16<<<2304,  256, 0, stream>>>(ws1, ws1h, 589824);
    cvt_f32_f16<<<2304,  256, 0, stream>>>(ws2, ws2h, 589824);

    // routing (atomic-free count + low-contention scatter)
    gate_kernel<<<2048, 256, 0, stream>>>(x, gw, tidx, tw);
    count_kernel<<<1, 1024, 0, stream>>>(tidx, cnt, base, cur);
    scatter_kernel<<<32, 256, 0, stream>>>(tidx, tw, cur, rowsIdx, rw, tslot);

    // shared expert, then routed; FC2R writes weighted f16 into yb
    // routed grid.x: sum_e ceil(cnt_e/256) <= 64 + 8 = 72
    gemm_kernel<FC1S><<<dim3(32, 24), 512, 0, stream>>>(xh, ws1h, bs1, h, out, cnt, base, rowsIdx, rw);
    gemm_kernel<FC2S><<<dim3(32, 6),  512, 0, stream>>>(h,  ws2h, bs2, h, out, cnt, base, rowsIdx, rw);
    gemm_kernel<FC1R><<<dim3(72, 24), 512, 0, stream>>>(xh, w1h,  b1,  h, out, cnt, base, rowsIdx, rw);
    gemm_kernel<FC2R><<<dim3(72, 6),  512, 0, stream>>>(h,  w2h,  b2,  yb, out, cnt, base, rowsIdx, rw);

    // final combine: out[t] += y[slot0] + y[slot1]
    combine_kernel<<<3072, 256, 0, stream>>>(yb, tslot, out);
}